// Round 1
// baseline (2929.502 us; speedup 1.0000x reference)
//
#include <hip/hip_runtime.h>
#include <cstddef>

// TAGConv K=2: out = concat(x, Px, P^2 x) @ W^T + b
// P = mean over incoming edges: (Pv)[d] = (1/max(deg_in(d),1)) * sum_{(s,d)} v[s]
//
// Baseline round: atomicAdd scatter for the two propagations, LDS-tiled fp32
// GEMM for the 50000x384 @ 384x128 projection.

#define DFEAT 128

// ---- degree: deg[d] += 1 per edge -------------------------------------------
__global__ void deg_kernel(const int* __restrict__ dst, float* __restrict__ deg, int E) {
    int e = blockIdx.x * blockDim.x + threadIdx.x;
    if (e < E) atomicAdd(&deg[dst[e]], 1.0f);
}

// ---- inv[i] = 1 / max(deg[i], 1)  (in place) --------------------------------
__global__ void inv_kernel(float* __restrict__ deg, int N) {
    int i = blockIdx.x * blockDim.x + threadIdx.x;
    if (i < N) deg[i] = 1.0f / fmaxf(deg[i], 1.0f);
}

// ---- scatter: accum[dst] += feat[src] * (scale ? scale[src] : 1) ------------
// 32 threads per edge, one float4 each (128 floats/row).
__global__ void scatter_kernel(const float* __restrict__ feat,
                               const float* __restrict__ scale,   // may be null
                               const int* __restrict__ srcIdx,
                               const int* __restrict__ dstIdx,
                               float* __restrict__ accum, int E) {
    int gid = blockIdx.x * blockDim.x + threadIdx.x;
    int e = gid >> 5;
    int part = gid & 31;
    if (e >= E) return;
    int s = srcIdx[e];
    int d = dstIdx[e];
    const float4 v = reinterpret_cast<const float4*>(feat + (size_t)s * DFEAT)[part];
    float sc = scale ? scale[s] : 1.0f;
    float* dp = accum + (size_t)d * DFEAT + part * 4;
    atomicAdd(dp + 0, v.x * sc);
    atomicAdd(dp + 1, v.y * sc);
    atomicAdd(dp + 2, v.z * sc);
    atomicAdd(dp + 3, v.w * sc);
}

// ---- GEMM: out[n, c] = b[c] + sum_k h[n,k] * W[c,k] -------------------------
// h = concat(x, p1*inv, p2*inv), K=384. Tile: 32 nodes x 128 cols per block,
// 256 threads, each thread owns 16 rows x 1 col. K-chunks of 32 staged in LDS.
__global__ __launch_bounds__(256) void gemm_kernel(
    const float* __restrict__ x, const float* __restrict__ p1,
    const float* __restrict__ p2, const float* __restrict__ inv,
    const float* __restrict__ W, const float* __restrict__ bias,
    float* __restrict__ out, int N) {
    __shared__ float hT[32][33];    // [row][kk]
    __shared__ float wT[128][33];   // [col][kk]

    const int t = threadIdx.x;
    const int c = t & 127;
    const int rg = t >> 7;          // 0 or 1 -> rows rg*16..rg*16+15
    const int nodeBase = blockIdx.x * 32;

    float acc[16];
#pragma unroll
    for (int i = 0; i < 16; ++i) acc[i] = 0.0f;

    for (int chunk = 0; chunk < 12; ++chunk) {
        const int k0 = chunk * 32;
        const int fs = k0 >> 7;      // 0: x, 1: p1, 2: p2
        const int ko = k0 & 127;
        const float* srcf = (fs == 0) ? x : (fs == 1 ? p1 : p2);

        // stage h tile: 32 rows x 32 k (each thread: one float4)
        {
            const int row = t >> 3;
            const int q = t & 7;
            int node = nodeBase + row;
            int nodeC = node < N ? node : N - 1;
            float sc = (fs == 0) ? 1.0f : inv[nodeC];
            const float4 v = *reinterpret_cast<const float4*>(
                srcf + (size_t)nodeC * DFEAT + ko + q * 4);
            hT[row][q * 4 + 0] = v.x * sc;
            hT[row][q * 4 + 1] = v.y * sc;
            hT[row][q * 4 + 2] = v.z * sc;
            hT[row][q * 4 + 3] = v.w * sc;
        }
        // stage W tile: 128 cols x 32 k
#pragma unroll
        for (int it = 0; it < 4; ++it) {
            const int idx = it * 256 + t;
            const int c2 = idx >> 3;
            const int q = idx & 7;
            const float4 v = *reinterpret_cast<const float4*>(
                W + (size_t)c2 * 384 + k0 + q * 4);
            wT[c2][q * 4 + 0] = v.x;
            wT[c2][q * 4 + 1] = v.y;
            wT[c2][q * 4 + 2] = v.z;
            wT[c2][q * 4 + 3] = v.w;
        }
        __syncthreads();

#pragma unroll
        for (int kk = 0; kk < 32; ++kk) {
            const float wv = wT[c][kk];
#pragma unroll
            for (int i = 0; i < 16; ++i)
                acc[i] = fmaf(hT[rg * 16 + i][kk], wv, acc[i]);
        }
        __syncthreads();
    }

    const float bv = bias[c];
#pragma unroll
    for (int i = 0; i < 16; ++i) {
        const int node = nodeBase + rg * 16 + i;
        if (node < N) out[(size_t)node * DFEAT + c] = acc[i] + bv;
    }
}

extern "C" void kernel_launch(void* const* d_in, const int* in_sizes, int n_in,
                              void* d_out, int out_size, void* d_ws, size_t ws_size,
                              hipStream_t stream) {
    (void)n_in; (void)out_size; (void)ws_size;
    const float* x  = (const float*)d_in[0];
    const int*   ei = (const int*)d_in[1];
    const float* W  = (const float*)d_in[2];
    const float* b  = (const float*)d_in[3];
    float* out = (float*)d_out;

    const int N = in_sizes[0] / DFEAT;
    const int E = in_sizes[1] / 2;
    const int* src = ei;
    const int* dst = ei + E;

    // workspace layout: [inv (N floats, 256B-aligned)] [p1 (N*128)] [p2 (N*128)]
    float* inv = (float*)d_ws;
    const size_t A = (((size_t)N * sizeof(float) + 255) / 256) * 256;
    float* p1 = (float*)((char*)d_ws + A);
    float* p2 = p1 + (size_t)N * DFEAT;
    const size_t totalBytes = A + 2ull * (size_t)N * DFEAT * sizeof(float);

    hipMemsetAsync(d_ws, 0, totalBytes, stream);

    deg_kernel<<<(E + 255) / 256, 256, 0, stream>>>(dst, inv, E);
    inv_kernel<<<(N + 255) / 256, 256, 0, stream>>>(inv, N);

    const int scatterBlocks = (int)(((size_t)E * 32 + 255) / 256);
    scatter_kernel<<<scatterBlocks, 256, 0, stream>>>(x, nullptr, src, dst, p1, E);
    scatter_kernel<<<scatterBlocks, 256, 0, stream>>>(p1, inv, src, dst, p2, E);

    gemm_kernel<<<(N + 31) / 32, 256, 0, stream>>>(x, p1, p2, inv, W, b, out, N);
}

// Round 2
// 402.473 us; speedup vs baseline: 7.2788x; 7.2788x over previous
//
#include <hip/hip_runtime.h>
#include <cstddef>

// TAGConv K=2: out = concat(x, m1, m2) @ W^T + b
//   m1[d] = mean_{(s,d)} x[s],  m2[d] = mean_{(s,d)} m1[s]
//
// R2: CSR build (histogram + scan + slot scatter) and atomic-free per-node
// gather; means stored normalized so downstream needs no inv scaling.

#define DFEAT 128

// ---- int histogram of dst ---------------------------------------------------
__global__ void hist_kernel(const int* __restrict__ dst, int* __restrict__ deg, int E) {
    int e = blockIdx.x * blockDim.x + threadIdx.x;
    if (e < E) atomicAdd(&deg[dst[e]], 1);
}

// ---- scan stage 1: per-256-block exclusive scan + block sums; also inv ------
__global__ __launch_bounds__(256) void scan1_kernel(const int* __restrict__ deg,
                                                    int* __restrict__ partial,
                                                    int* __restrict__ blockSums,
                                                    float* __restrict__ inv, int N) {
    __shared__ int s[256];
    const int t = threadIdx.x;
    const int i = blockIdx.x * 256 + t;
    const int v = (i < N) ? deg[i] : 0;
    s[t] = v;
    __syncthreads();
#pragma unroll
    for (int off = 1; off < 256; off <<= 1) {
        int x = (t >= off) ? s[t - off] : 0;
        __syncthreads();
        s[t] += x;
        __syncthreads();
    }
    if (i < N) {
        partial[i] = s[t] - v;                      // exclusive
        inv[i] = 1.0f / (float)max(v, 1);
    }
    if (t == 255) blockSums[blockIdx.x] = s[255];   // block total
}

// ---- scan stage 2: single-block inclusive scan of block sums ----------------
__global__ __launch_bounds__(256) void scan2_kernel(int* __restrict__ blockSums, int nb) {
    __shared__ int s[256];
    const int t = threadIdx.x;
    s[t] = (t < nb) ? blockSums[t] : 0;
    __syncthreads();
#pragma unroll
    for (int off = 1; off < 256; off <<= 1) {
        int x = (t >= off) ? s[t - off] : 0;
        __syncthreads();
        s[t] += x;
        __syncthreads();
    }
    if (t < nb) blockSums[t] = s[t];
}

// ---- scan stage 3: rowptr[i] = partial[i] + carry ---------------------------
__global__ void scan3_kernel(const int* __restrict__ partial,
                             const int* __restrict__ blockSums,
                             int* __restrict__ rowptr, int N, int E) {
    int i = blockIdx.x * blockDim.x + threadIdx.x;
    if (i < N) {
        int carry = (blockIdx.x > 0) ? blockSums[blockIdx.x - 1] : 0;
        rowptr[i] = partial[i] + carry;
    }
    if (i == 0) rowptr[N] = E;
}

// ---- slot scatter: col[rowptr[d] + cnt[d]++] = src[e] -----------------------
__global__ void csr_scatter_kernel(const int* __restrict__ src, const int* __restrict__ dst,
                                   const int* __restrict__ rowptr, int* __restrict__ cnt,
                                   int* __restrict__ col, int E) {
    int e = blockIdx.x * blockDim.x + threadIdx.x;
    if (e >= E) return;
    int d = dst[e];
    int pos = atomicAdd(&cnt[d], 1);
    col[rowptr[d] + pos] = src[e];
}

// ---- gather: out[n] = inv[n] * sum_{e in [rowptr[n],rowptr[n+1])} feat[col[e]]
// One 32-lane group per node; each lane owns one float4 of the 128-float row.
__global__ __launch_bounds__(256) void gather_kernel(const float* __restrict__ feat,
                                                     const int* __restrict__ rowptr,
                                                     const int* __restrict__ col,
                                                     const float* __restrict__ inv,
                                                     float* __restrict__ out, int N) {
    const int n = blockIdx.x * 8 + (threadIdx.x >> 5);
    const int part = threadIdx.x & 31;
    if (n >= N) return;
    const int beg = rowptr[n];
    const int end = rowptr[n + 1];
    float4 acc = make_float4(0.f, 0.f, 0.f, 0.f);
    int e = beg;
    for (; e + 1 < end; e += 2) {                     // unroll 2 for MLP
        const int s0 = col[e];
        const int s1 = col[e + 1];
        const float4 v0 = reinterpret_cast<const float4*>(feat + (size_t)s0 * DFEAT)[part];
        const float4 v1 = reinterpret_cast<const float4*>(feat + (size_t)s1 * DFEAT)[part];
        acc.x += v0.x + v1.x;
        acc.y += v0.y + v1.y;
        acc.z += v0.z + v1.z;
        acc.w += v0.w + v1.w;
    }
    if (e < end) {
        const int s0 = col[e];
        const float4 v0 = reinterpret_cast<const float4*>(feat + (size_t)s0 * DFEAT)[part];
        acc.x += v0.x; acc.y += v0.y; acc.z += v0.z; acc.w += v0.w;
    }
    const float sc = inv[n];
    reinterpret_cast<float4*>(out + (size_t)n * DFEAT)[part] =
        make_float4(acc.x * sc, acc.y * sc, acc.z * sc, acc.w * sc);
}

// ---- GEMM: out[n, c] = b[c] + sum_k h[n,k] * W[c,k],  h = [x | m1 | m2] -----
__global__ __launch_bounds__(256) void gemm_kernel(
    const float* __restrict__ x, const float* __restrict__ m1,
    const float* __restrict__ m2, const float* __restrict__ W,
    const float* __restrict__ bias, float* __restrict__ out, int N) {
    __shared__ float hT[32][33];
    __shared__ float wT[128][33];

    const int t = threadIdx.x;
    const int c = t & 127;
    const int rg = t >> 7;
    const int nodeBase = blockIdx.x * 32;

    float acc[16];
#pragma unroll
    for (int i = 0; i < 16; ++i) acc[i] = 0.0f;

    for (int chunk = 0; chunk < 12; ++chunk) {
        const int k0 = chunk * 32;
        const int fs = k0 >> 7;
        const int ko = k0 & 127;
        const float* srcf = (fs == 0) ? x : (fs == 1 ? m1 : m2);

        {
            const int row = t >> 3;
            const int q = t & 7;
            int node = nodeBase + row;
            int nodeC = node < N ? node : N - 1;
            const float4 v = *reinterpret_cast<const float4*>(
                srcf + (size_t)nodeC * DFEAT + ko + q * 4);
            hT[row][q * 4 + 0] = v.x;
            hT[row][q * 4 + 1] = v.y;
            hT[row][q * 4 + 2] = v.z;
            hT[row][q * 4 + 3] = v.w;
        }
#pragma unroll
        for (int it = 0; it < 4; ++it) {
            const int idx = it * 256 + t;
            const int c2 = idx >> 3;
            const int q = idx & 7;
            const float4 v = *reinterpret_cast<const float4*>(
                W + (size_t)c2 * 384 + k0 + q * 4);
            wT[c2][q * 4 + 0] = v.x;
            wT[c2][q * 4 + 1] = v.y;
            wT[c2][q * 4 + 2] = v.z;
            wT[c2][q * 4 + 3] = v.w;
        }
        __syncthreads();

#pragma unroll
        for (int kk = 0; kk < 32; ++kk) {
            const float wv = wT[c][kk];
#pragma unroll
            for (int i = 0; i < 16; ++i)
                acc[i] = fmaf(hT[rg * 16 + i][kk], wv, acc[i]);
        }
        __syncthreads();
    }

    const float bv = bias[c];
#pragma unroll
    for (int i = 0; i < 16; ++i) {
        const int node = nodeBase + rg * 16 + i;
        if (node < N) out[(size_t)node * DFEAT + c] = acc[i] + bv;
    }
}

extern "C" void kernel_launch(void* const* d_in, const int* in_sizes, int n_in,
                              void* d_out, int out_size, void* d_ws, size_t ws_size,
                              hipStream_t stream) {
    (void)n_in; (void)out_size; (void)ws_size;
    const float* x  = (const float*)d_in[0];
    const int*   ei = (const int*)d_in[1];
    const float* W  = (const float*)d_in[2];
    const float* b  = (const float*)d_in[3];
    float* out = (float*)d_out;

    const int N = in_sizes[0] / DFEAT;
    const int E = in_sizes[1] / 2;
    const int* src = ei;
    const int* dst = ei + E;
    const int nb = (N + 255) / 256;     // scan blocks (196 for N=50000, <=256)

    // ---- workspace layout (all 256B-aligned) ----
    auto up = [](size_t v) { return (v + 255) & ~(size_t)255; };
    char* p = (char*)d_ws;
    int*   deg       = (int*)p;          p += up((size_t)N * 4);        // zeroed
    int*   cnt       = (int*)p;          p += up((size_t)N * 4);        // zeroed
    const size_t zeroBytes = (size_t)(p - (char*)d_ws);
    int*   partial   = (int*)p;          p += up((size_t)N * 4);
    int*   blockSums = (int*)p;          p += up(256 * 4);
    int*   rowptr    = (int*)p;          p += up(((size_t)N + 1) * 4);
    int*   col       = (int*)p;          p += up((size_t)E * 4);
    float* inv       = (float*)p;        p += up((size_t)N * 4);
    float* m1        = (float*)p;        p += up((size_t)N * DFEAT * 4);
    float* m2        = (float*)p;        p += up((size_t)N * DFEAT * 4);

    hipMemsetAsync(d_ws, 0, zeroBytes, stream);

    hist_kernel<<<(E + 255) / 256, 256, 0, stream>>>(dst, deg, E);
    scan1_kernel<<<nb, 256, 0, stream>>>(deg, partial, blockSums, inv, N);
    scan2_kernel<<<1, 256, 0, stream>>>(blockSums, nb);
    scan3_kernel<<<nb, 256, 0, stream>>>(partial, blockSums, rowptr, N, E);
    csr_scatter_kernel<<<(E + 255) / 256, 256, 0, stream>>>(src, dst, rowptr, cnt, col, E);

    const int gatherBlocks = (N + 7) / 8;     // 8 nodes (32 lanes each) per block
    gather_kernel<<<gatherBlocks, 256, 0, stream>>>(x,  rowptr, col, inv, m1, N);
    gather_kernel<<<gatherBlocks, 256, 0, stream>>>(m1, rowptr, col, inv, m2, N);

    gemm_kernel<<<(N + 31) / 32, 256, 0, stream>>>(x, m1, m2, W, b, out, N);
}

// Round 5
// 285.839 us; speedup vs baseline: 10.2488x; 1.4080x over previous
//
#include <hip/hip_runtime.h>
#include <cstddef>

// TAGConv K=2: out = concat(x, m1, m2) @ W^T + b
//   m1[d] = mean_{(s,d)} x[s],  m2[d] = mean_{(s,d)} m1[s]
//
// R3 (2nd resubmit; prior two benches died on broker infra): register-blocked
// fp32 GEMM (64x128 tile, 8x4 acc/thread, transposed LDS tiles, b128 LDS
// reads). CSR build + gather unchanged from R2.

#define DFEAT 128

// ---- int histogram of dst ---------------------------------------------------
__global__ void hist_kernel(const int* __restrict__ dst, int* __restrict__ deg, int E) {
    int e = blockIdx.x * blockDim.x + threadIdx.x;
    if (e < E) atomicAdd(&deg[dst[e]], 1);
}

// ---- scan stage 1: per-256-block exclusive scan + block sums; also inv ------
__global__ __launch_bounds__(256) void scan1_kernel(const int* __restrict__ deg,
                                                    int* __restrict__ partial,
                                                    int* __restrict__ blockSums,
                                                    float* __restrict__ inv, int N) {
    __shared__ int s[256];
    const int t = threadIdx.x;
    const int i = blockIdx.x * 256 + t;
    const int v = (i < N) ? deg[i] : 0;
    s[t] = v;
    __syncthreads();
#pragma unroll
    for (int off = 1; off < 256; off <<= 1) {
        int x = (t >= off) ? s[t - off] : 0;
        __syncthreads();
        s[t] += x;
        __syncthreads();
    }
    if (i < N) {
        partial[i] = s[t] - v;                      // exclusive
        inv[i] = 1.0f / (float)max(v, 1);
    }
    if (t == 255) blockSums[blockIdx.x] = s[255];   // block total
}

// ---- scan stage 2: single-block inclusive scan of block sums ----------------
__global__ __launch_bounds__(256) void scan2_kernel(int* __restrict__ blockSums, int nb) {
    __shared__ int s[256];
    const int t = threadIdx.x;
    s[t] = (t < nb) ? blockSums[t] : 0;
    __syncthreads();
#pragma unroll
    for (int off = 1; off < 256; off <<= 1) {
        int x = (t >= off) ? s[t - off] : 0;
        __syncthreads();
        s[t] += x;
        __syncthreads();
    }
    if (t < nb) blockSums[t] = s[t];
}

// ---- scan stage 3: rowptr[i] = partial[i] + carry ---------------------------
__global__ void scan3_kernel(const int* __restrict__ partial,
                             const int* __restrict__ blockSums,
                             int* __restrict__ rowptr, int N, int E) {
    int i = blockIdx.x * blockDim.x + threadIdx.x;
    if (i < N) {
        int carry = (blockIdx.x > 0) ? blockSums[blockIdx.x - 1] : 0;
        rowptr[i] = partial[i] + carry;
    }
    if (i == 0) rowptr[N] = E;
}

// ---- slot scatter: col[rowptr[d] + cnt[d]++] = src[e] -----------------------
__global__ void csr_scatter_kernel(const int* __restrict__ src, const int* __restrict__ dst,
                                   const int* __restrict__ rowptr, int* __restrict__ cnt,
                                   int* __restrict__ col, int E) {
    int e = blockIdx.x * blockDim.x + threadIdx.x;
    if (e >= E) return;
    int d = dst[e];
    int pos = atomicAdd(&cnt[d], 1);
    col[rowptr[d] + pos] = src[e];
}

// ---- gather: out[n] = inv[n] * sum_{e in [rowptr[n],rowptr[n+1])} feat[col[e]]
__global__ __launch_bounds__(256) void gather_kernel(const float* __restrict__ feat,
                                                     const int* __restrict__ rowptr,
                                                     const int* __restrict__ col,
                                                     const float* __restrict__ inv,
                                                     float* __restrict__ out, int N) {
    const int n = blockIdx.x * 8 + (threadIdx.x >> 5);
    const int part = threadIdx.x & 31;
    if (n >= N) return;
    const int beg = rowptr[n];
    const int end = rowptr[n + 1];
    float4 acc = make_float4(0.f, 0.f, 0.f, 0.f);
    int e = beg;
    for (; e + 1 < end; e += 2) {
        const int s0 = col[e];
        const int s1 = col[e + 1];
        const float4 v0 = reinterpret_cast<const float4*>(feat + (size_t)s0 * DFEAT)[part];
        const float4 v1 = reinterpret_cast<const float4*>(feat + (size_t)s1 * DFEAT)[part];
        acc.x += v0.x + v1.x;
        acc.y += v0.y + v1.y;
        acc.z += v0.z + v1.z;
        acc.w += v0.w + v1.w;
    }
    if (e < end) {
        const int s0 = col[e];
        const float4 v0 = reinterpret_cast<const float4*>(feat + (size_t)s0 * DFEAT)[part];
        acc.x += v0.x; acc.y += v0.y; acc.z += v0.z; acc.w += v0.w;
    }
    const float sc = inv[n];
    reinterpret_cast<float4*>(out + (size_t)n * DFEAT)[part] =
        make_float4(acc.x * sc, acc.y * sc, acc.z * sc, acc.w * sc);
}

// ---- GEMM: out[n, c] = b[c] + sum_k h[n,k] * W[c,k],  h = [x | m1 | m2] -----
// Tile: 64 rows x 128 cols per block, 256 threads, 8x4 acc per thread.
// LDS tiles stored k-major (transposed) so inner loop is 3x ds_read_b128.
__global__ __launch_bounds__(256) void gemm_kernel(
    const float* __restrict__ x, const float* __restrict__ m1,
    const float* __restrict__ m2, const float* __restrict__ W,
    const float* __restrict__ bias, float* __restrict__ out, int N) {
    __shared__ float hTt[32][64];    // [kk][row]
    __shared__ float wTt[32][128];   // [kk][col]

    const int t = threadIdx.x;
    const int cg = t & 31;           // col group: cols cg*4 .. cg*4+3
    const int rg = t >> 5;           // row group: rows rg*8 .. rg*8+7
    const int nodeBase = blockIdx.x * 64;

    float acc[8][4];
#pragma unroll
    for (int i = 0; i < 8; ++i)
#pragma unroll
        for (int j = 0; j < 4; ++j) acc[i][j] = 0.0f;

    // h staging assignment: row = idx & 63, q = idx >> 6 (2 iters)
    const int hRow = t & 63;
    // W staging assignment: c = idx & 127, q = idx >> 7 (4 iters)
    const int wc = t & 127;

    for (int chunk = 0; chunk < 12; ++chunk) {
        const int k0 = chunk * 32;
        const int fs = chunk >> 2;       // 0:x 1:m1 2:m2
        const int ko = k0 & 127;
        const float* srcf = (fs == 0) ? x : (fs == 1 ? m1 : m2);

        // stage h tile: 64 rows x 32 k, transposed into hTt[k][row]
        {
            int node = nodeBase + hRow;
            int nodeC = node < N ? node : N - 1;
            const float* rp = srcf + (size_t)nodeC * DFEAT + ko;
#pragma unroll
            for (int it = 0; it < 2; ++it) {
                const int q = it * 4 + (t >> 6);           // 0..7
                const float4 v = *reinterpret_cast<const float4*>(rp + q * 4);
                hTt[q * 4 + 0][hRow] = v.x;
                hTt[q * 4 + 1][hRow] = v.y;
                hTt[q * 4 + 2][hRow] = v.z;
                hTt[q * 4 + 3][hRow] = v.w;
            }
        }
        // stage W tile: 128 cols x 32 k, transposed into wTt[k][col]
        {
            const float* wp = W + (size_t)wc * 384 + k0;
#pragma unroll
            for (int it = 0; it < 4; ++it) {
                const int q = it * 2 + (t >> 7);           // 0..7
                const float4 v = *reinterpret_cast<const float4*>(wp + q * 4);
                wTt[q * 4 + 0][wc] = v.x;
                wTt[q * 4 + 1][wc] = v.y;
                wTt[q * 4 + 2][wc] = v.z;
                wTt[q * 4 + 3][wc] = v.w;
            }
        }
        __syncthreads();

#pragma unroll
        for (int kk = 0; kk < 32; ++kk) {
            const float4 h0 = *reinterpret_cast<const float4*>(&hTt[kk][rg * 8]);
            const float4 h1 = *reinterpret_cast<const float4*>(&hTt[kk][rg * 8 + 4]);
            const float4 wv = *reinterpret_cast<const float4*>(&wTt[kk][cg * 4]);
            const float hr[8] = {h0.x, h0.y, h0.z, h0.w, h1.x, h1.y, h1.z, h1.w};
            const float wr[4] = {wv.x, wv.y, wv.z, wv.w};
#pragma unroll
            for (int i = 0; i < 8; ++i)
#pragma unroll
                for (int j = 0; j < 4; ++j)
                    acc[i][j] = fmaf(hr[i], wr[j], acc[i][j]);
        }
        __syncthreads();
    }

    const float4 bv = *reinterpret_cast<const float4*>(bias + cg * 4);
#pragma unroll
    for (int i = 0; i < 8; ++i) {
        const int node = nodeBase + rg * 8 + i;
        if (node < N) {
            float4 o;
            o.x = acc[i][0] + bv.x;
            o.y = acc[i][1] + bv.y;
            o.z = acc[i][2] + bv.z;
            o.w = acc[i][3] + bv.w;
            *reinterpret_cast<float4*>(out + (size_t)node * DFEAT + cg * 4) = o;
        }
    }
}

extern "C" void kernel_launch(void* const* d_in, const int* in_sizes, int n_in,
                              void* d_out, int out_size, void* d_ws, size_t ws_size,
                              hipStream_t stream) {
    (void)n_in; (void)out_size; (void)ws_size;
    const float* x  = (const float*)d_in[0];
    const int*   ei = (const int*)d_in[1];
    const float* W  = (const float*)d_in[2];
    const float* b  = (const float*)d_in[3];
    float* out = (float*)d_out;

    const int N = in_sizes[0] / DFEAT;
    const int E = in_sizes[1] / 2;
    const int* src = ei;
    const int* dst = ei + E;
    const int nb = (N + 255) / 256;

    auto up = [](size_t v) { return (v + 255) & ~(size_t)255; };
    char* p = (char*)d_ws;
    int*   deg       = (int*)p;          p += up((size_t)N * 4);        // zeroed
    int*   cnt       = (int*)p;          p += up((size_t)N * 4);        // zeroed
    const size_t zeroBytes = (size_t)(p - (char*)d_ws);
    int*   partial   = (int*)p;          p += up((size_t)N * 4);
    int*   blockSums = (int*)p;          p += up(256 * 4);
    int*   rowptr    = (int*)p;          p += up(((size_t)N + 1) * 4);
    int*   col       = (int*)p;          p += up((size_t)E * 4);
    float* inv       = (float*)p;        p += up((size_t)N * 4);
    float* m1        = (float*)p;        p += up((size_t)N * DFEAT * 4);
    float* m2        = (float*)p;        p += up((size_t)N * DFEAT * 4);

    hipMemsetAsync(d_ws, 0, zeroBytes, stream);

    hist_kernel<<<(E + 255) / 256, 256, 0, stream>>>(dst, deg, E);
    scan1_kernel<<<nb, 256, 0, stream>>>(deg, partial, blockSums, inv, N);
    scan2_kernel<<<1, 256, 0, stream>>>(blockSums, nb);
    scan3_kernel<<<nb, 256, 0, stream>>>(partial, blockSums, rowptr, N, E);
    csr_scatter_kernel<<<(E + 255) / 256, 256, 0, stream>>>(src, dst, rowptr, cnt, col, E);

    const int gatherBlocks = (N + 7) / 8;
    gather_kernel<<<gatherBlocks, 256, 0, stream>>>(x,  rowptr, col, inv, m1, N);
    gather_kernel<<<gatherBlocks, 256, 0, stream>>>(m1, rowptr, col, inv, m2, N);

    gemm_kernel<<<(N + 63) / 64, 256, 0, stream>>>(x, m1, m2, W, b, out, N);
}

// Round 8
// 215.844 us; speedup vs baseline: 13.5723x; 1.3243x over previous
//
#include <hip/hip_runtime.h>
#include <cstddef>

// TAGConv K=2: out = concat(x, m1, m2) @ W^T + b
// R6 (3rd submit; prior two benches died on broker infra): bf16 feature
// pipeline + MFMA GEMM.
//   - x, W converted to bf16 once per call
//   - gathers read/write bf16 rows (256B/row), accumulate fp32
//   - GEMM: v_mfma_f32_16x16x32_bf16, fragments loaded straight from
//     global (16B contiguous per lane) -> no LDS, no barriers.

#define DFEAT 128

typedef __attribute__((ext_vector_type(8))) short short8v;  // 8 bf16 = 4 VGPR
typedef __attribute__((ext_vector_type(4))) float f32x4;

__device__ inline unsigned short f2bf(float f) {   // RNE f32 -> bf16
    unsigned int u;
    __builtin_memcpy(&u, &f, 4);
    unsigned int r = u + 0x7FFFu + ((u >> 16) & 1u);
    return (unsigned short)(r >> 16);
}
__device__ inline float bf2f(unsigned short h) {
    unsigned int u = ((unsigned int)h) << 16;
    float f;
    __builtin_memcpy(&f, &u, 4);
    return f;
}

// ---- fp32 -> bf16 pack (4 elems/thread) -------------------------------------
__global__ void conv_bf16_kernel(const float* __restrict__ in,
                                 unsigned short* __restrict__ outb, int total4) {
    int i = blockIdx.x * blockDim.x + threadIdx.x;
    if (i >= total4) return;
    const float4 v = reinterpret_cast<const float4*>(in)[i];
    unsigned int w0 = (unsigned int)f2bf(v.x) | ((unsigned int)f2bf(v.y) << 16);
    unsigned int w1 = (unsigned int)f2bf(v.z) | ((unsigned int)f2bf(v.w) << 16);
    reinterpret_cast<uint2*>(outb)[i] = make_uint2(w0, w1);
}

// ---- int histogram of dst ---------------------------------------------------
__global__ void hist_kernel(const int* __restrict__ dst, int* __restrict__ deg, int E) {
    int e = blockIdx.x * blockDim.x + threadIdx.x;
    if (e < E) atomicAdd(&deg[dst[e]], 1);
}

// ---- scan stage 1 -----------------------------------------------------------
__global__ __launch_bounds__(256) void scan1_kernel(const int* __restrict__ deg,
                                                    int* __restrict__ partial,
                                                    int* __restrict__ blockSums,
                                                    float* __restrict__ inv, int N) {
    __shared__ int s[256];
    const int t = threadIdx.x;
    const int i = blockIdx.x * 256 + t;
    const int v = (i < N) ? deg[i] : 0;
    s[t] = v;
    __syncthreads();
#pragma unroll
    for (int off = 1; off < 256; off <<= 1) {
        int x = (t >= off) ? s[t - off] : 0;
        __syncthreads();
        s[t] += x;
        __syncthreads();
    }
    if (i < N) {
        partial[i] = s[t] - v;
        inv[i] = 1.0f / (float)max(v, 1);
    }
    if (t == 255) blockSums[blockIdx.x] = s[255];
}

// ---- scan stage 2 -----------------------------------------------------------
__global__ __launch_bounds__(256) void scan2_kernel(int* __restrict__ blockSums, int nb) {
    __shared__ int s[256];
    const int t = threadIdx.x;
    s[t] = (t < nb) ? blockSums[t] : 0;
    __syncthreads();
#pragma unroll
    for (int off = 1; off < 256; off <<= 1) {
        int x = (t >= off) ? s[t - off] : 0;
        __syncthreads();
        s[t] += x;
        __syncthreads();
    }
    if (t < nb) blockSums[t] = s[t];
}

// ---- scan stage 3 -----------------------------------------------------------
__global__ void scan3_kernel(const int* __restrict__ partial,
                             const int* __restrict__ blockSums,
                             int* __restrict__ rowptr, int N, int E) {
    int i = blockIdx.x * blockDim.x + threadIdx.x;
    if (i < N) {
        int carry = (blockIdx.x > 0) ? blockSums[blockIdx.x - 1] : 0;
        rowptr[i] = partial[i] + carry;
    }
    if (i == 0) rowptr[N] = E;
}

// ---- slot scatter -----------------------------------------------------------
__global__ void csr_scatter_kernel(const int* __restrict__ src, const int* __restrict__ dst,
                                   const int* __restrict__ rowptr, int* __restrict__ cnt,
                                   int* __restrict__ col, int E) {
    int e = blockIdx.x * blockDim.x + threadIdx.x;
    if (e >= E) return;
    int d = dst[e];
    int pos = atomicAdd(&cnt[d], 1);
    col[rowptr[d] + pos] = src[e];
}

// ---- bf16 gather: outb[n] = bf16( inv[n] * sum feat[col[e]] ) ---------------
// 16 lanes per node, each lane owns 8 bf16 (16B) of the 256B row.
__global__ __launch_bounds__(256) void gather_bf16_kernel(
    const unsigned short* __restrict__ feat, const int* __restrict__ rowptr,
    const int* __restrict__ col, const float* __restrict__ inv,
    unsigned short* __restrict__ outb, int N) {
    const int n = blockIdx.x * 16 + (threadIdx.x >> 4);
    const int lane = threadIdx.x & 15;
    if (n >= N) return;
    const int beg = rowptr[n];
    const int end = rowptr[n + 1];
    float acc[8];
#pragma unroll
    for (int j = 0; j < 8; ++j) acc[j] = 0.0f;
    int e = beg;
    for (; e + 1 < end; e += 2) {
        const int s0 = col[e];
        const int s1 = col[e + 1];
        const short8v v0 = *reinterpret_cast<const short8v*>(
            feat + (size_t)s0 * DFEAT + lane * 8);
        const short8v v1 = *reinterpret_cast<const short8v*>(
            feat + (size_t)s1 * DFEAT + lane * 8);
#pragma unroll
        for (int j = 0; j < 8; ++j)
            acc[j] += bf2f((unsigned short)v0[j]) + bf2f((unsigned short)v1[j]);
    }
    if (e < end) {
        const int s0 = col[e];
        const short8v v0 = *reinterpret_cast<const short8v*>(
            feat + (size_t)s0 * DFEAT + lane * 8);
#pragma unroll
        for (int j = 0; j < 8; ++j) acc[j] += bf2f((unsigned short)v0[j]);
    }
    const float sc = inv[n];
    unsigned int w[4];
#pragma unroll
    for (int j = 0; j < 4; ++j) {
        w[j] = (unsigned int)f2bf(acc[2 * j] * sc) |
               ((unsigned int)f2bf(acc[2 * j + 1] * sc) << 16);
    }
    *reinterpret_cast<uint4*>(outb + (size_t)n * DFEAT + lane * 8) =
        make_uint4(w[0], w[1], w[2], w[3]);
}

// ---- MFMA GEMM: out[n,c] = b[c] + sum_k h[n,k] * W[c,k] ---------------------
// h = [xb | m1b | m2b] bf16, W bf16. Block: 64 rows x 128 cols, 4 waves.
// Wave w owns rows [base+w*16, +16) x all 128 cols = 8 accumulator tiles.
// Fragment layouts (v_mfma_f32_16x16x32_bf16, m89-verified C/D):
//   A: row = lane&15,      k = (lane>>4)*8 + j   (j=0..7, 16B contiguous)
//   B: col = lane&15,      k = (lane>>4)*8 + j   (= W[col][k], 16B contiguous)
//   D: col = lane&15,      row = (lane>>4)*4 + r
__global__ __launch_bounds__(256) void gemm_mfma_kernel(
    const unsigned short* __restrict__ xb, const unsigned short* __restrict__ m1b,
    const unsigned short* __restrict__ m2b, const unsigned short* __restrict__ Wb,
    const float* __restrict__ bias, float* __restrict__ out, int N) {
    const int t = threadIdx.x;
    const int w = t >> 6;
    const int l = t & 63;
    const int lr = l & 15;
    const int kg = l >> 4;
    const int rowBase = blockIdx.x * 64 + w * 16;
    int arow = rowBase + lr;
    if (arow >= N) arow = N - 1;      // clamp (duplicate read, store is guarded)

    f32x4 acc[8];
#pragma unroll
    for (int nt = 0; nt < 8; ++nt) acc[nt] = (f32x4){0.f, 0.f, 0.f, 0.f};

#pragma unroll
    for (int ks = 0; ks < 12; ++ks) {
        const unsigned short* feat = (ks < 4) ? xb : (ks < 8 ? m1b : m2b);
        const int k0 = (ks & 3) * 32;
        const short8v a = *reinterpret_cast<const short8v*>(
            feat + (size_t)arow * DFEAT + k0 + kg * 8);
#pragma unroll
        for (int nt = 0; nt < 8; ++nt) {
            const int bcol = nt * 16 + lr;
            const short8v b = *reinterpret_cast<const short8v*>(
                Wb + (size_t)bcol * 384 + ks * 32 + kg * 8);
            acc[nt] = __builtin_amdgcn_mfma_f32_16x16x32_bf16(a, b, acc[nt], 0, 0, 0);
        }
    }

#pragma unroll
    for (int nt = 0; nt < 8; ++nt) {
        const int c = nt * 16 + lr;
        const float bv = bias[c];
#pragma unroll
        for (int r = 0; r < 4; ++r) {
            const int node = rowBase + kg * 4 + r;
            if (node < N) out[(size_t)node * DFEAT + c] = acc[nt][r] + bv;
        }
    }
}

extern "C" void kernel_launch(void* const* d_in, const int* in_sizes, int n_in,
                              void* d_out, int out_size, void* d_ws, size_t ws_size,
                              hipStream_t stream) {
    (void)n_in; (void)out_size; (void)ws_size;
    const float* x  = (const float*)d_in[0];
    const int*   ei = (const int*)d_in[1];
    const float* W  = (const float*)d_in[2];
    const float* b  = (const float*)d_in[3];
    float* out = (float*)d_out;

    const int N = in_sizes[0] / DFEAT;
    const int E = in_sizes[1] / 2;
    const int* src = ei;
    const int* dst = ei + E;
    const int nb = (N + 255) / 256;

    auto up = [](size_t v) { return (v + 255) & ~(size_t)255; };
    char* p = (char*)d_ws;
    int*   deg       = (int*)p;            p += up((size_t)N * 4);     // zeroed
    int*   cnt       = (int*)p;            p += up((size_t)N * 4);     // zeroed
    const size_t zeroBytes = (size_t)(p - (char*)d_ws);
    int*   partial   = (int*)p;            p += up((size_t)N * 4);
    int*   blockSums = (int*)p;            p += up(256 * 4);
    int*   rowptr    = (int*)p;            p += up(((size_t)N + 1) * 4);
    int*   col       = (int*)p;            p += up((size_t)E * 4);
    float* inv       = (float*)p;          p += up((size_t)N * 4);
    unsigned short* xb  = (unsigned short*)p;  p += up((size_t)N * DFEAT * 2);
    unsigned short* m1b = (unsigned short*)p;  p += up((size_t)N * DFEAT * 2);
    unsigned short* m2b = (unsigned short*)p;  p += up((size_t)N * DFEAT * 2);
    unsigned short* Wb  = (unsigned short*)p;  p += up((size_t)DFEAT * 384 * 2);

    hipMemsetAsync(d_ws, 0, zeroBytes, stream);

    hist_kernel<<<(E + 255) / 256, 256, 0, stream>>>(dst, deg, E);
    scan1_kernel<<<nb, 256, 0, stream>>>(deg, partial, blockSums, inv, N);
    scan2_kernel<<<1, 256, 0, stream>>>(blockSums, nb);
    scan3_kernel<<<nb, 256, 0, stream>>>(partial, blockSums, rowptr, N, E);
    csr_scatter_kernel<<<(E + 255) / 256, 256, 0, stream>>>(src, dst, rowptr, cnt, col, E);

    const int x4 = N * DFEAT / 4;
    conv_bf16_kernel<<<(x4 + 255) / 256, 256, 0, stream>>>(x, xb, x4);
    const int w4 = DFEAT * 384 / 4;
    conv_bf16_kernel<<<(w4 + 255) / 256, 256, 0, stream>>>(W, Wb, w4);

    const int gatherBlocks = (N + 15) / 16;   // 16 nodes/block (16 lanes each)
    gather_bf16_kernel<<<gatherBlocks, 256, 0, stream>>>(xb,  rowptr, col, inv, m1b, N);
    gather_bf16_kernel<<<gatherBlocks, 256, 0, stream>>>(m1b, rowptr, col, inv, m2b, N);

    gemm_mfma_kernel<<<(N + 63) / 64, 256, 0, stream>>>(xb, m1b, m2b, Wb, b, out, N);
}

// Round 9
// 189.740 us; speedup vs baseline: 15.4395x; 1.1376x over previous
//
#include <hip/hip_runtime.h>
#include <cstddef>

// TAGConv K=2: out = concat(x, m1, m2) @ W^T + b
// R9: W pre-packed into MFMA fragment order -> all B-loads in the GEMM are
// lane-contiguous 1KiB coalesced streams (R8 was latency-bound on scattered
// 16B L2 reads). bf16 gathers + CSR build unchanged from R8.

#define DFEAT 128

typedef __attribute__((ext_vector_type(8))) short short8v;  // 8 bf16 = 4 VGPR
typedef __attribute__((ext_vector_type(4))) float f32x4;

__device__ inline unsigned short f2bf(float f) {   // RNE f32 -> bf16
    unsigned int u;
    __builtin_memcpy(&u, &f, 4);
    unsigned int r = u + 0x7FFFu + ((u >> 16) & 1u);
    return (unsigned short)(r >> 16);
}
__device__ inline float bf2f(unsigned short h) {
    unsigned int u = ((unsigned int)h) << 16;
    float f;
    __builtin_memcpy(&f, &u, 4);
    return f;
}

// ---- fp32 -> bf16 pack (4 elems/thread) -------------------------------------
__global__ void conv_bf16_kernel(const float* __restrict__ in,
                                 unsigned short* __restrict__ outb, int total4) {
    int i = blockIdx.x * blockDim.x + threadIdx.x;
    if (i >= total4) return;
    const float4 v = reinterpret_cast<const float4*>(in)[i];
    unsigned int w0 = (unsigned int)f2bf(v.x) | ((unsigned int)f2bf(v.y) << 16);
    unsigned int w1 = (unsigned int)f2bf(v.z) | ((unsigned int)f2bf(v.w) << 16);
    reinterpret_cast<uint2*>(outb)[i] = make_uint2(w0, w1);
}

// ---- pack W (fp32 [128][384]) into MFMA-fragment-ordered bf16 ---------------
// Wpk element layout: ((ks*8 + nt)*64 + lane)*8 + j  ==  bf16 of
//   W[nt*16 + (lane&15)][ks*32 + (lane>>4)*8 + j]
__global__ void pack_w_kernel(const float* __restrict__ W,
                              unsigned short* __restrict__ Wpk) {
    const int idx = blockIdx.x * blockDim.x + threadIdx.x;   // 12*8*64 = 6144
    if (idx >= 6144) return;
    const int lane = idx & 63;
    const int nt = (idx >> 6) & 7;
    const int ks = idx >> 9;
    const int col = nt * 16 + (lane & 15);
    const int k = ks * 32 + (lane >> 4) * 8;
    const float* wp = W + (size_t)col * 384 + k;
    unsigned int w[4];
#pragma unroll
    for (int j = 0; j < 4; ++j) {
        w[j] = (unsigned int)f2bf(wp[2 * j]) |
               ((unsigned int)f2bf(wp[2 * j + 1]) << 16);
    }
    *reinterpret_cast<uint4*>(Wpk + (size_t)idx * 8) = make_uint4(w[0], w[1], w[2], w[3]);
}

// ---- int histogram of dst ---------------------------------------------------
__global__ void hist_kernel(const int* __restrict__ dst, int* __restrict__ deg, int E) {
    int e = blockIdx.x * blockDim.x + threadIdx.x;
    if (e < E) atomicAdd(&deg[dst[e]], 1);
}

// ---- scan stage 1 -----------------------------------------------------------
__global__ __launch_bounds__(256) void scan1_kernel(const int* __restrict__ deg,
                                                    int* __restrict__ partial,
                                                    int* __restrict__ blockSums,
                                                    float* __restrict__ inv, int N) {
    __shared__ int s[256];
    const int t = threadIdx.x;
    const int i = blockIdx.x * 256 + t;
    const int v = (i < N) ? deg[i] : 0;
    s[t] = v;
    __syncthreads();
#pragma unroll
    for (int off = 1; off < 256; off <<= 1) {
        int x = (t >= off) ? s[t - off] : 0;
        __syncthreads();
        s[t] += x;
        __syncthreads();
    }
    if (i < N) {
        partial[i] = s[t] - v;
        inv[i] = 1.0f / (float)max(v, 1);
    }
    if (t == 255) blockSums[blockIdx.x] = s[255];
}

// ---- scan stage 2 -----------------------------------------------------------
__global__ __launch_bounds__(256) void scan2_kernel(int* __restrict__ blockSums, int nb) {
    __shared__ int s[256];
    const int t = threadIdx.x;
    s[t] = (t < nb) ? blockSums[t] : 0;
    __syncthreads();
#pragma unroll
    for (int off = 1; off < 256; off <<= 1) {
        int x = (t >= off) ? s[t - off] : 0;
        __syncthreads();
        s[t] += x;
        __syncthreads();
    }
    if (t < nb) blockSums[t] = s[t];
}

// ---- scan stage 3 -----------------------------------------------------------
__global__ void scan3_kernel(const int* __restrict__ partial,
                             const int* __restrict__ blockSums,
                             int* __restrict__ rowptr, int N, int E) {
    int i = blockIdx.x * blockDim.x + threadIdx.x;
    if (i < N) {
        int carry = (blockIdx.x > 0) ? blockSums[blockIdx.x - 1] : 0;
        rowptr[i] = partial[i] + carry;
    }
    if (i == 0) rowptr[N] = E;
}

// ---- slot scatter -----------------------------------------------------------
__global__ void csr_scatter_kernel(const int* __restrict__ src, const int* __restrict__ dst,
                                   const int* __restrict__ rowptr, int* __restrict__ cnt,
                                   int* __restrict__ col, int E) {
    int e = blockIdx.x * blockDim.x + threadIdx.x;
    if (e >= E) return;
    int d = dst[e];
    int pos = atomicAdd(&cnt[d], 1);
    col[rowptr[d] + pos] = src[e];
}

// ---- bf16 gather: outb[n] = bf16( inv[n] * sum feat[col[e]] ) ---------------
// 16 lanes per node, each lane owns 8 bf16 (16B) of the 256B row.
__global__ __launch_bounds__(256) void gather_bf16_kernel(
    const unsigned short* __restrict__ feat, const int* __restrict__ rowptr,
    const int* __restrict__ col, const float* __restrict__ inv,
    unsigned short* __restrict__ outb, int N) {
    const int n = blockIdx.x * 16 + (threadIdx.x >> 4);
    const int lane = threadIdx.x & 15;
    if (n >= N) return;
    const int beg = rowptr[n];
    const int end = rowptr[n + 1];
    float acc[8];
#pragma unroll
    for (int j = 0; j < 8; ++j) acc[j] = 0.0f;
    int e = beg;
    for (; e + 1 < end; e += 2) {
        const int s0 = col[e];
        const int s1 = col[e + 1];
        const short8v v0 = *reinterpret_cast<const short8v*>(
            feat + (size_t)s0 * DFEAT + lane * 8);
        const short8v v1 = *reinterpret_cast<const short8v*>(
            feat + (size_t)s1 * DFEAT + lane * 8);
#pragma unroll
        for (int j = 0; j < 8; ++j)
            acc[j] += bf2f((unsigned short)v0[j]) + bf2f((unsigned short)v1[j]);
    }
    if (e < end) {
        const int s0 = col[e];
        const short8v v0 = *reinterpret_cast<const short8v*>(
            feat + (size_t)s0 * DFEAT + lane * 8);
#pragma unroll
        for (int j = 0; j < 8; ++j) acc[j] += bf2f((unsigned short)v0[j]);
    }
    const float sc = inv[n];
    unsigned int w[4];
#pragma unroll
    for (int j = 0; j < 4; ++j) {
        w[j] = (unsigned int)f2bf(acc[2 * j] * sc) |
               ((unsigned int)f2bf(acc[2 * j + 1] * sc) << 16);
    }
    *reinterpret_cast<uint4*>(outb + (size_t)n * DFEAT + lane * 8) =
        make_uint4(w[0], w[1], w[2], w[3]);
}

// ---- MFMA GEMM: out[n,c] = b[c] + sum_k h[n,k] * W[c,k] ---------------------
// h = [xb | m1b | m2b] bf16. W pre-packed in fragment order (Wpk).
// Block: 64 rows x 128 cols, 4 waves; wave w owns rows [base+w*16, +16).
// Per ks: 1 A-load (64B/row segments) + 8 coalesced 1KiB B-loads + 8 MFMAs.
__global__ __launch_bounds__(256) void gemm_mfma_kernel(
    const unsigned short* __restrict__ xb, const unsigned short* __restrict__ m1b,
    const unsigned short* __restrict__ m2b, const unsigned short* __restrict__ Wpk,
    const float* __restrict__ bias, float* __restrict__ out, int N) {
    const int t = threadIdx.x;
    const int w = t >> 6;
    const int l = t & 63;
    const int lr = l & 15;
    const int kg = l >> 4;
    const int rowBase = blockIdx.x * 64 + w * 16;
    int arow = rowBase + lr;
    if (arow >= N) arow = N - 1;      // clamp (duplicate read, store is guarded)

    const short8v* Wv = reinterpret_cast<const short8v*>(Wpk);

    f32x4 acc[8];
#pragma unroll
    for (int nt = 0; nt < 8; ++nt) acc[nt] = (f32x4){0.f, 0.f, 0.f, 0.f};

#pragma unroll
    for (int ks = 0; ks < 12; ++ks) {
        const unsigned short* feat = (ks < 4) ? xb : (ks < 8 ? m1b : m2b);
        const int k0 = (ks & 3) * 32;
        const short8v a = *reinterpret_cast<const short8v*>(
            feat + (size_t)arow * DFEAT + k0 + kg * 8);
        short8v bfrag[8];
#pragma unroll
        for (int nt = 0; nt < 8; ++nt)
            bfrag[nt] = Wv[(ks * 8 + nt) * 64 + l];
#pragma unroll
        for (int nt = 0; nt < 8; ++nt)
            acc[nt] = __builtin_amdgcn_mfma_f32_16x16x32_bf16(a, bfrag[nt], acc[nt], 0, 0, 0);
    }

#pragma unroll
    for (int nt = 0; nt < 8; ++nt) {
        const int c = nt * 16 + lr;
        const float bv = bias[c];
#pragma unroll
        for (int r = 0; r < 4; ++r) {
            const int node = rowBase + kg * 4 + r;
            if (node < N) out[(size_t)node * DFEAT + c] = acc[nt][r] + bv;
        }
    }
}

extern "C" void kernel_launch(void* const* d_in, const int* in_sizes, int n_in,
                              void* d_out, int out_size, void* d_ws, size_t ws_size,
                              hipStream_t stream) {
    (void)n_in; (void)out_size; (void)ws_size;
    const float* x  = (const float*)d_in[0];
    const int*   ei = (const int*)d_in[1];
    const float* W  = (const float*)d_in[2];
    const float* b  = (const float*)d_in[3];
    float* out = (float*)d_out;

    const int N = in_sizes[0] / DFEAT;
    const int E = in_sizes[1] / 2;
    const int* src = ei;
    const int* dst = ei + E;
    const int nb = (N + 255) / 256;

    auto up = [](size_t v) { return (v + 255) & ~(size_t)255; };
    char* p = (char*)d_ws;
    int*   deg       = (int*)p;            p += up((size_t)N * 4);     // zeroed
    int*   cnt       = (int*)p;            p += up((size_t)N * 4);     // zeroed
    const size_t zeroBytes = (size_t)(p - (char*)d_ws);
    int*   partial   = (int*)p;            p += up((size_t)N * 4);
    int*   blockSums = (int*)p;            p += up(256 * 4);
    int*   rowptr    = (int*)p;            p += up(((size_t)N + 1) * 4);
    int*   col       = (int*)p;            p += up((size_t)E * 4);
    float* inv       = (float*)p;          p += up((size_t)N * 4);
    unsigned short* xb  = (unsigned short*)p;  p += up((size_t)N * DFEAT * 2);
    unsigned short* m1b = (unsigned short*)p;  p += up((size_t)N * DFEAT * 2);
    unsigned short* m2b = (unsigned short*)p;  p += up((size_t)N * DFEAT * 2);
    unsigned short* Wpk = (unsigned short*)p;  p += up((size_t)6144 * 8 * 2);

    hipMemsetAsync(d_ws, 0, zeroBytes, stream);

    hist_kernel<<<(E + 255) / 256, 256, 0, stream>>>(dst, deg, E);
    scan1_kernel<<<nb, 256, 0, stream>>>(deg, partial, blockSums, inv, N);
    scan2_kernel<<<1, 256, 0, stream>>>(blockSums, nb);
    scan3_kernel<<<nb, 256, 0, stream>>>(partial, blockSums, rowptr, N, E);
    csr_scatter_kernel<<<(E + 255) / 256, 256, 0, stream>>>(src, dst, rowptr, cnt, col, E);

    const int x4 = N * DFEAT / 4;
    conv_bf16_kernel<<<(x4 + 255) / 256, 256, 0, stream>>>(x, xb, x4);
    pack_w_kernel<<<(6144 + 255) / 256, 256, 0, stream>>>(W, Wpk);

    const int gatherBlocks = (N + 15) / 16;   // 16 nodes/block (16 lanes each)
    gather_bf16_kernel<<<gatherBlocks, 256, 0, stream>>>(xb,  rowptr, col, inv, m1b, N);
    gather_bf16_kernel<<<gatherBlocks, 256, 0, stream>>>(m1b, rowptr, col, inv, m2b, N);

    gemm_mfma_kernel<<<(N + 63) / 64, 256, 0, stream>>>(xb, m1b, m2b, Wpk, b, out, N);
}

// Round 10
// 184.110 us; speedup vs baseline: 15.9117x; 1.0306x over previous
//
#include <hip/hip_runtime.h>
#include <cstddef>

// TAGConv K=2: out = concat(x, m1, m2) @ W^T + b
// R10: slot-scatter rewritten as 8 XCD-pinned "teams" (blockIdx%8), each
// owning 1/8 of the dst space -> col cache lines are written by a single
// XCD's L2, eliminating the 17x cross-XCD partial-line write amplification
// seen in R9 (WRITE_SIZE 55MB for 3.2MB of data). Rest unchanged from R9.

#define DFEAT 128
#define NTEAMS 8
#define BPT 128   // blocks per team

typedef __attribute__((ext_vector_type(8))) short short8v;  // 8 bf16 = 4 VGPR
typedef __attribute__((ext_vector_type(4))) float f32x4;

__device__ inline unsigned short f2bf(float f) {   // RNE f32 -> bf16
    unsigned int u;
    __builtin_memcpy(&u, &f, 4);
    unsigned int r = u + 0x7FFFu + ((u >> 16) & 1u);
    return (unsigned short)(r >> 16);
}
__device__ inline float bf2f(unsigned short h) {
    unsigned int u = ((unsigned int)h) << 16;
    float f;
    __builtin_memcpy(&f, &u, 4);
    return f;
}

// ---- fp32 -> bf16 pack (4 elems/thread) -------------------------------------
__global__ void conv_bf16_kernel(const float* __restrict__ in,
                                 unsigned short* __restrict__ outb, int total4) {
    int i = blockIdx.x * blockDim.x + threadIdx.x;
    if (i >= total4) return;
    const float4 v = reinterpret_cast<const float4*>(in)[i];
    unsigned int w0 = (unsigned int)f2bf(v.x) | ((unsigned int)f2bf(v.y) << 16);
    unsigned int w1 = (unsigned int)f2bf(v.z) | ((unsigned int)f2bf(v.w) << 16);
    reinterpret_cast<uint2*>(outb)[i] = make_uint2(w0, w1);
}

// ---- pack W (fp32 [128][384]) into MFMA-fragment-ordered bf16 ---------------
// Wpk element layout: ((ks*8 + nt)*64 + lane)*8 + j  ==  bf16 of
//   W[nt*16 + (lane&15)][ks*32 + (lane>>4)*8 + j]
__global__ void pack_w_kernel(const float* __restrict__ W,
                              unsigned short* __restrict__ Wpk) {
    const int idx = blockIdx.x * blockDim.x + threadIdx.x;   // 12*8*64 = 6144
    if (idx >= 6144) return;
    const int lane = idx & 63;
    const int nt = (idx >> 6) & 7;
    const int ks = idx >> 9;
    const int col = nt * 16 + (lane & 15);
    const int k = ks * 32 + (lane >> 4) * 8;
    const float* wp = W + (size_t)col * 384 + k;
    unsigned int w[4];
#pragma unroll
    for (int j = 0; j < 4; ++j) {
        w[j] = (unsigned int)f2bf(wp[2 * j]) |
               ((unsigned int)f2bf(wp[2 * j + 1]) << 16);
    }
    *reinterpret_cast<uint4*>(Wpk + (size_t)idx * 8) = make_uint4(w[0], w[1], w[2], w[3]);
}

// ---- int histogram of dst ---------------------------------------------------
__global__ void hist_kernel(const int* __restrict__ dst, int* __restrict__ deg, int E) {
    int e = blockIdx.x * blockDim.x + threadIdx.x;
    if (e < E) atomicAdd(&deg[dst[e]], 1);
}

// ---- scan stage 1 -----------------------------------------------------------
__global__ __launch_bounds__(256) void scan1_kernel(const int* __restrict__ deg,
                                                    int* __restrict__ partial,
                                                    int* __restrict__ blockSums,
                                                    float* __restrict__ inv, int N) {
    __shared__ int s[256];
    const int t = threadIdx.x;
    const int i = blockIdx.x * 256 + t;
    const int v = (i < N) ? deg[i] : 0;
    s[t] = v;
    __syncthreads();
#pragma unroll
    for (int off = 1; off < 256; off <<= 1) {
        int x = (t >= off) ? s[t - off] : 0;
        __syncthreads();
        s[t] += x;
        __syncthreads();
    }
    if (i < N) {
        partial[i] = s[t] - v;
        inv[i] = 1.0f / (float)max(v, 1);
    }
    if (t == 255) blockSums[blockIdx.x] = s[255];
}

// ---- scan stage 2 -----------------------------------------------------------
__global__ __launch_bounds__(256) void scan2_kernel(int* __restrict__ blockSums, int nb) {
    __shared__ int s[256];
    const int t = threadIdx.x;
    s[t] = (t < nb) ? blockSums[t] : 0;
    __syncthreads();
#pragma unroll
    for (int off = 1; off < 256; off <<= 1) {
        int x = (t >= off) ? s[t - off] : 0;
        __syncthreads();
        s[t] += x;
        __syncthreads();
    }
    if (t < nb) blockSums[t] = s[t];
}

// ---- scan stage 3 -----------------------------------------------------------
__global__ void scan3_kernel(const int* __restrict__ partial,
                             const int* __restrict__ blockSums,
                             int* __restrict__ rowptr, int N, int E) {
    int i = blockIdx.x * blockDim.x + threadIdx.x;
    if (i < N) {
        int carry = (blockIdx.x > 0) ? blockSums[blockIdx.x - 1] : 0;
        rowptr[i] = partial[i] + carry;
    }
    if (i == 0) rowptr[N] = E;
}

// ---- team slot scatter ------------------------------------------------------
// Team r = blocks with blockIdx%8==r (lands on XCD r per the measured MI355X
// round-robin map; perf heuristic only). Team r scans ALL edges (disjoint
// chunks across its 128 blocks) and scatters only those with dst in its node
// range. All writes to a col region thus come from one XCD -> lines fill in
// one L2 and write back once.
__global__ void csr_scatter_team_kernel(const int* __restrict__ src,
                                        const int* __restrict__ dst,
                                        const int* __restrict__ rowptr,
                                        int* __restrict__ cnt,
                                        int* __restrict__ col, int E, int N) {
    const int r = blockIdx.x & (NTEAMS - 1);
    const int q = blockIdx.x >> 3;
    const int nchunk = (N + NTEAMS - 1) / NTEAMS;
    const int lo = r * nchunk;
    const int hi = min(lo + nchunk, N);
    const int echunk = (E + BPT - 1) / BPT;
    const int e0 = q * echunk;
    const int e1 = min(e0 + echunk, E);
    for (int e = e0 + (int)threadIdx.x; e < e1; e += (int)blockDim.x) {
        const int d = dst[e];
        if (d >= lo && d < hi) {
            const int pos = atomicAdd(&cnt[d], 1);
            col[rowptr[d] + pos] = src[e];
        }
    }
}

// ---- bf16 gather: outb[n] = bf16( inv[n] * sum feat[col[e]] ) ---------------
// 16 lanes per node, each lane owns 8 bf16 (16B) of the 256B row.
__global__ __launch_bounds__(256) void gather_bf16_kernel(
    const unsigned short* __restrict__ feat, const int* __restrict__ rowptr,
    const int* __restrict__ col, const float* __restrict__ inv,
    unsigned short* __restrict__ outb, int N) {
    const int n = blockIdx.x * 16 + (threadIdx.x >> 4);
    const int lane = threadIdx.x & 15;
    if (n >= N) return;
    const int beg = rowptr[n];
    const int end = rowptr[n + 1];
    float acc[8];
#pragma unroll
    for (int j = 0; j < 8; ++j) acc[j] = 0.0f;
    int e = beg;
    for (; e + 1 < end; e += 2) {
        const int s0 = col[e];
        const int s1 = col[e + 1];
        const short8v v0 = *reinterpret_cast<const short8v*>(
            feat + (size_t)s0 * DFEAT + lane * 8);
        const short8v v1 = *reinterpret_cast<const short8v*>(
            feat + (size_t)s1 * DFEAT + lane * 8);
#pragma unroll
        for (int j = 0; j < 8; ++j)
            acc[j] += bf2f((unsigned short)v0[j]) + bf2f((unsigned short)v1[j]);
    }
    if (e < end) {
        const int s0 = col[e];
        const short8v v0 = *reinterpret_cast<const short8v*>(
            feat + (size_t)s0 * DFEAT + lane * 8);
#pragma unroll
        for (int j = 0; j < 8; ++j) acc[j] += bf2f((unsigned short)v0[j]);
    }
    const float sc = inv[n];
    unsigned int w[4];
#pragma unroll
    for (int j = 0; j < 4; ++j) {
        w[j] = (unsigned int)f2bf(acc[2 * j] * sc) |
               ((unsigned int)f2bf(acc[2 * j + 1] * sc) << 16);
    }
    *reinterpret_cast<uint4*>(outb + (size_t)n * DFEAT + lane * 8) =
        make_uint4(w[0], w[1], w[2], w[3]);
}

// ---- MFMA GEMM: out[n,c] = b[c] + sum_k h[n,k] * W[c,k] ---------------------
// h = [xb | m1b | m2b] bf16. W pre-packed in fragment order (Wpk).
// Block: 64 rows x 128 cols, 4 waves; wave w owns rows [base+w*16, +16).
__global__ __launch_bounds__(256) void gemm_mfma_kernel(
    const unsigned short* __restrict__ xb, const unsigned short* __restrict__ m1b,
    const unsigned short* __restrict__ m2b, const unsigned short* __restrict__ Wpk,
    const float* __restrict__ bias, float* __restrict__ out, int N) {
    const int t = threadIdx.x;
    const int w = t >> 6;
    const int l = t & 63;
    const int lr = l & 15;
    const int kg = l >> 4;
    const int rowBase = blockIdx.x * 64 + w * 16;
    int arow = rowBase + lr;
    if (arow >= N) arow = N - 1;      // clamp (duplicate read, store is guarded)

    const short8v* Wv = reinterpret_cast<const short8v*>(Wpk);

    f32x4 acc[8];
#pragma unroll
    for (int nt = 0; nt < 8; ++nt) acc[nt] = (f32x4){0.f, 0.f, 0.f, 0.f};

#pragma unroll
    for (int ks = 0; ks < 12; ++ks) {
        const unsigned short* feat = (ks < 4) ? xb : (ks < 8 ? m1b : m2b);
        const int k0 = (ks & 3) * 32;
        const short8v a = *reinterpret_cast<const short8v*>(
            feat + (size_t)arow * DFEAT + k0 + kg * 8);
        short8v bfrag[8];
#pragma unroll
        for (int nt = 0; nt < 8; ++nt)
            bfrag[nt] = Wv[(ks * 8 + nt) * 64 + l];
#pragma unroll
        for (int nt = 0; nt < 8; ++nt)
            acc[nt] = __builtin_amdgcn_mfma_f32_16x16x32_bf16(a, bfrag[nt], acc[nt], 0, 0, 0);
    }

#pragma unroll
    for (int nt = 0; nt < 8; ++nt) {
        const int c = nt * 16 + lr;
        const float bv = bias[c];
#pragma unroll
        for (int r = 0; r < 4; ++r) {
            const int node = rowBase + kg * 4 + r;
            if (node < N) out[(size_t)node * DFEAT + c] = acc[nt][r] + bv;
        }
    }
}

extern "C" void kernel_launch(void* const* d_in, const int* in_sizes, int n_in,
                              void* d_out, int out_size, void* d_ws, size_t ws_size,
                              hipStream_t stream) {
    (void)n_in; (void)out_size; (void)ws_size;
    const float* x  = (const float*)d_in[0];
    const int*   ei = (const int*)d_in[1];
    const float* W  = (const float*)d_in[2];
    const float* b  = (const float*)d_in[3];
    float* out = (float*)d_out;

    const int N = in_sizes[0] / DFEAT;
    const int E = in_sizes[1] / 2;
    const int* src = ei;
    const int* dst = ei + E;
    const int nb = (N + 255) / 256;

    auto up = [](size_t v) { return (v + 255) & ~(size_t)255; };
    char* p = (char*)d_ws;
    int*   deg       = (int*)p;            p += up((size_t)N * 4);     // zeroed
    int*   cnt       = (int*)p;            p += up((size_t)N * 4);     // zeroed
    const size_t zeroBytes = (size_t)(p - (char*)d_ws);
    int*   partial   = (int*)p;            p += up((size_t)N * 4);
    int*   blockSums = (int*)p;            p += up(256 * 4);
    int*   rowptr    = (int*)p;            p += up(((size_t)N + 1) * 4);
    int*   col       = (int*)p;            p += up((size_t)E * 4);
    float* inv       = (float*)p;          p += up((size_t)N * 4);
    unsigned short* xb  = (unsigned short*)p;  p += up((size_t)N * DFEAT * 2);
    unsigned short* m1b = (unsigned short*)p;  p += up((size_t)N * DFEAT * 2);
    unsigned short* m2b = (unsigned short*)p;  p += up((size_t)N * DFEAT * 2);
    unsigned short* Wpk = (unsigned short*)p;  p += up((size_t)6144 * 8 * 2);

    hipMemsetAsync(d_ws, 0, zeroBytes, stream);

    hist_kernel<<<(E + 255) / 256, 256, 0, stream>>>(dst, deg, E);
    scan1_kernel<<<nb, 256, 0, stream>>>(deg, partial, blockSums, inv, N);
    scan2_kernel<<<1, 256, 0, stream>>>(blockSums, nb);
    scan3_kernel<<<nb, 256, 0, stream>>>(partial, blockSums, rowptr, N, E);
    csr_scatter_team_kernel<<<NTEAMS * BPT, 256, 0, stream>>>(src, dst, rowptr, cnt, col, E, N);

    const int x4 = N * DFEAT / 4;
    conv_bf16_kernel<<<(x4 + 255) / 256, 256, 0, stream>>>(x, xb, x4);
    pack_w_kernel<<<(6144 + 255) / 256, 256, 0, stream>>>(W, Wpk);

    const int gatherBlocks = (N + 15) / 16;   // 16 nodes/block (16 lanes each)
    gather_bf16_kernel<<<gatherBlocks, 256, 0, stream>>>(xb,  rowptr, col, inv, m1b, N);
    gather_bf16_kernel<<<gatherBlocks, 256, 0, stream>>>(m1b, rowptr, col, inv, m2b, N);

    gemm_mfma_kernel<<<(N + 63) / 64, 256, 0, stream>>>(xb, m1b, m2b, Wpk, b, out, N);
}